// Round 1
// baseline (822.135 us; speedup 1.0000x reference)
//
#include <hip/hip_runtime.h>
#include <math.h>

#define BB 8
#define PP 5
#define QQ 75
#define CC 640
#define HW 49
#define NIMG_Q (BB*QQ)     // 600
#define NIMG_S (BB*PP)     // 40
#define NPROB  (BB*QQ*PP)  // 3000
#define TEMP 12.5f

// workspace layout (float offsets); total ~769K floats ~ 3.1 MB
#define OFF_SGAP   0
#define OFF_QGAP   (OFF_SGAP  + NIMG_S*CC)
#define OFF_SMEAN  (OFF_QGAP  + NIMG_Q*CC)
#define OFF_SINV   (OFF_SMEAN + NIMG_S*HW)
#define OFF_QMEAN  (OFF_SINV  + NIMG_S*HW)
#define OFF_QINV   (OFF_QMEAN + NIMG_Q*HW)
#define OFF_MARGA  (OFF_QINV  + NIMG_Q*HW)
#define OFF_MARGB  (OFF_MARGA + NPROB*HW)
#define OFF_LOGITS (OFF_MARGB + NPROB*HW)

__device__ __forceinline__ float wsum64(float v) {
#pragma unroll
    for (int off = 32; off > 0; off >>= 1) v += __shfl_xor(v, off, 64);
    return v;
}

// ---------------- Kernel 1: per-image stats ----------------
// grid = 640 (600 query imgs + 40 support imgs), block = 64
__global__ __launch_bounds__(64) void stats_kernel(const float* __restrict__ sup,
                                                   const float* __restrict__ qry,
                                                   float* __restrict__ ws) {
    int img = blockIdx.x;
    int lane = threadIdx.x;
    const float* X;
    float *gap, *cmean, *cinv;
    if (img < NIMG_Q) {
        X = qry + (size_t)img * CC * HW;
        gap = ws + OFF_QGAP + img * CC;
        cmean = ws + OFF_QMEAN + img * HW;
        cinv = ws + OFF_QINV + img * HW;
    } else {
        int i = img - NIMG_Q;
        X = sup + (size_t)i * CC * HW;
        gap = ws + OFF_SGAP + i * CC;
        cmean = ws + OFF_SMEAN + i * HW;
        cinv = ws + OFF_SINV + i * HW;
    }
    // pass A: column (spatial) stats over channels
    if (lane < HW) {
        float cs = 0.f, sq = 0.f;
        for (int c = 0; c < CC; c++) {
            float v = X[c * HW + lane];
            cs += v;
            sq = fmaf(v, v, sq);
        }
        float mu = cs * (1.0f / CC);
        float nsq = fmaxf(sq - cs * cs * (1.0f / CC), 0.f);
        cmean[lane] = mu;
        cinv[lane] = 1.0f / fmaxf(sqrtf(nsq), 1e-8f);
    }
    // pass B: GAP vector (mean over spatial)
    for (int cc = 0; cc < CC / 64; cc++) {
        int c = cc * 64 + lane;
        float s = 0.f;
        for (int m = 0; m < HW; m++) s += X[c * HW + m];
        gap[c] = s * (1.0f / HW);
    }
}

// ---------------- Kernel 2: row marginals a (query side, w1) ----------------
// grid = 600 (b,q), block = 64
__global__ __launch_bounds__(64) void marga_kernel(const float* __restrict__ qry,
                                                   float* __restrict__ ws) {
    int bq = blockIdx.x;
    int b = bq / QQ;
    int lane = threadIdx.x;
    const float* X = qry + (size_t)bq * CC * HW;
    const float* sg = ws + OFF_SGAP + b * PP * CC;
    float acc[PP] = {0.f, 0.f, 0.f, 0.f, 0.f};
    if (lane < HW) {
        for (int c = 0; c < CC; c++) {
            float v = X[c * HW + lane];
#pragma unroll
            for (int p = 0; p < PP; p++) acc[p] = fmaf(v, sg[p * CC + c], acc[p]);
        }
    }
#pragma unroll
    for (int p = 0; p < PP; p++) {
        float w = (lane < HW) ? (fmaxf(acc[p], 0.f) + 1.01e-3f) : 0.f;
        float s = wsum64(w);
        if (lane < HW) ws[OFF_MARGA + (bq * PP + p) * HW + lane] = w / s;
    }
}

// ---------------- Kernel 3: col marginals b (support side, w2) ----------------
// grid = 200 = (b*P+p)*5 + qchunk, block = 64; 15 q's per block
__global__ __launch_bounds__(64) void margb_kernel(const float* __restrict__ sup,
                                                   float* __restrict__ ws) {
    int id = blockIdx.x;
    int qc = id % 5;
    int bp = id / 5;
    int b = bp / PP;
    int p = bp % PP;
    int lane = threadIdx.x;
    const float* X = sup + (size_t)bp * CC * HW;
    const float* qg = ws + OFF_QGAP + (b * QQ + qc * 15) * CC;
    float acc[15];
#pragma unroll
    for (int i = 0; i < 15; i++) acc[i] = 0.f;
    if (lane < HW) {
        for (int c = 0; c < CC; c++) {
            float sv = X[c * HW + lane];
#pragma unroll
            for (int qq = 0; qq < 15; qq++)
                acc[qq] = fmaf(sv, qg[qq * CC + c], acc[qq]);
        }
    }
#pragma unroll
    for (int qq = 0; qq < 15; qq++) {
        int q = qc * 15 + qq;
        float w = (lane < HW) ? (fmaxf(acc[qq], 0.f) + 1.01e-3f) : 0.f;
        float s = wsum64(w);
        if (lane < HW) ws[OFF_MARGB + ((b * QQ + q) * PP + p) * HW + lane] = w / s;
    }
}

// ---------------- Kernel 4: fused S-GEMM + Sinkhorn + logit ----------------
// grid = 3000 (one problem per block), block = 256
__global__ __launch_bounds__(256) void emd_kernel(const float* __restrict__ sup,
                                                  const float* __restrict__ qry,
                                                  float* __restrict__ ws) {
    __shared__ __align__(16) float As[32][64];
    __shared__ __align__(16) float Bs[32][64];
    __shared__ __align__(16) float S_lds[50][53];
    __shared__ __align__(16) float vbuf[52];
    __shared__ __align__(16) float ubuf[52];

    int prob = blockIdx.x;
    int p = prob % PP;
    int bq = prob / PP;          // b*75+q
    int b = bq / QQ;
    int tid = threadIdx.x;
    int lane = tid & 63;
    int wv = tid >> 6;
    int ty = tid >> 4;           // 0..15 -> m = 4ty+i
    int tx = tid & 15;           // 0..15 -> n = 4tx+j

    const float* Xq = qry + (size_t)bq * CC * HW;
    const float* Xs = sup + (size_t)(b * PP + p) * CC * HW;

    float qm = 0.f, qi = 0.f, sm = 0.f, si = 0.f;
    if (lane < HW) {
        qm = ws[OFF_QMEAN + bq * HW + lane];
        qi = ws[OFF_QINV + bq * HW + lane];
        sm = ws[OFF_SMEAN + (b * PP + p) * HW + lane];
        si = ws[OFF_SINV + (b * PP + p) * HW + lane];
    }

    float acc[4][4];
#pragma unroll
    for (int i = 0; i < 4; i++)
#pragma unroll
        for (int j = 0; j < 4; j++) acc[i][j] = 0.f;

    for (int c0 = 0; c0 < CC; c0 += 32) {
        __syncthreads();
        // stage normalized chunks: each wave loads 8 rows
        for (int cl = wv; cl < 32; cl += 4) {
            int c = c0 + cl;
            float av = 0.f, bv = 0.f;
            if (lane < HW) {
                av = (Xq[c * HW + lane] - qm) * qi;
                bv = (Xs[c * HW + lane] - sm) * si;
            }
            As[cl][lane] = av;
            Bs[cl][lane] = bv;
        }
        __syncthreads();
#pragma unroll
        for (int cl = 0; cl < 32; cl++) {
            float4 a4 = *(const float4*)&As[cl][4 * ty];
            float4 b4 = *(const float4*)&Bs[cl][4 * tx];
            float av[4] = {a4.x, a4.y, a4.z, a4.w};
            float bv[4] = {b4.x, b4.y, b4.z, b4.w};
#pragma unroll
            for (int i = 0; i < 4; i++)
#pragma unroll
                for (int j = 0; j < 4; j++) acc[i][j] = fmaf(av[i], bv[j], acc[i][j]);
        }
    }

    // write S into LDS
#pragma unroll
    for (int i = 0; i < 4; i++) {
#pragma unroll
        for (int j = 0; j < 4; j++) {
            int m = 4 * ty + i, n = 4 * tx + j;
            if (m < HW && n < HW) S_lds[m][n] = acc[i][j];
        }
    }
    __syncthreads();
    if (tid >= 64) return;  // waves 1..3 done; wave 0 runs Sinkhorn barrier-free

    float am = 0.f, bm = 0.f;
    if (lane < HW) {
        am = ws[OFF_MARGA + prob * HW + lane];
        bm = ws[OFF_MARGB + prob * HW + lane];
    }
    int lr = (lane < HW) ? lane : 0;

    // K row (kr) and K column (kt) in registers; K = exp((S-1)/eps) = exp(20S-20)
    float kr[52], kt[52];
#pragma unroll
    for (int j = 0; j < 52; j++) {
        float krv = 0.f, ktv = 0.f;
        if (j < HW) {
            krv = __expf(fmaf(20.f, S_lds[lr][j], -20.f));
            ktv = __expf(fmaf(20.f, S_lds[j][lr], -20.f));
        }
        bool act = (lane < HW);
        kr[j] = act ? krv : 0.f;
        kt[j] = act ? ktv : 0.f;
    }

    if (lane < 52) {
        vbuf[lane] = (lane < HW) ? 1.f : 0.f;
        ubuf[lane] = 0.f;
    }
    __threadfence_block();

    float u = 0.f;
    for (int it = 0; it < 100; it++) {
        // u = a / (K v)
        float t0 = 0.f, t1 = 0.f, t2 = 0.f, t3 = 0.f;
#pragma unroll
        for (int g = 0; g < 13; g++) {
            float4 v4 = *(const float4*)&vbuf[4 * g];
            t0 = fmaf(kr[4 * g + 0], v4.x, t0);
            t1 = fmaf(kr[4 * g + 1], v4.y, t1);
            t2 = fmaf(kr[4 * g + 2], v4.z, t2);
            t3 = fmaf(kr[4 * g + 3], v4.w, t3);
        }
        float t = (t0 + t1) + (t2 + t3);
        u = am * __builtin_amdgcn_rcpf(t);
        if (lane < HW) ubuf[lane] = u;
        __threadfence_block();
        // v = b / (K^T u)
        float s0 = 0.f, s1 = 0.f, s2 = 0.f, s3 = 0.f;
#pragma unroll
        for (int g = 0; g < 13; g++) {
            float4 u4 = *(const float4*)&ubuf[4 * g];
            s0 = fmaf(kt[4 * g + 0], u4.x, s0);
            s1 = fmaf(kt[4 * g + 1], u4.y, s1);
            s2 = fmaf(kt[4 * g + 2], u4.z, s2);
            s3 = fmaf(kt[4 * g + 3], u4.w, s3);
        }
        float t2s = (s0 + s1) + (s2 + s3);
        float v = bm * __builtin_amdgcn_rcpf(t2s);
        if (lane < HW) vbuf[lane] = v;
        __threadfence_block();
    }

    // logit = T * sum_{m,n} S_mn * u_m K_mn v_n
    float ssum = 0.f;
#pragma unroll
    for (int g = 0; g < 13; g++) {
        float4 v4 = *(const float4*)&vbuf[4 * g];
        float vv[4] = {v4.x, v4.y, v4.z, v4.w};
#pragma unroll
        for (int k = 0; k < 4; k++) {
            int j = 4 * g + k;
            if (j < HW) ssum = fmaf(S_lds[lr][j] * kr[j], vv[k], ssum);
        }
    }
    float contrib = (lane < HW) ? (u * ssum) : 0.f;
    float tot = wsum64(contrib);
    if (lane == 0) ws[OFF_LOGITS + prob] = TEMP * tot;
}

// ---------------- Kernel 5: cross-entropy loss ----------------
// grid = 1, block = 640
__global__ __launch_bounds__(640) void loss_kernel(const float* __restrict__ ws,
                                                   const int* __restrict__ qy,
                                                   float* __restrict__ out) {
    int tid = threadIdx.x;
    float val = 0.f;
    if (tid < NIMG_Q) {
        const float* lg = ws + OFF_LOGITS + tid * PP;
        float l[PP];
        float mx = -1e30f;
#pragma unroll
        for (int p = 0; p < PP; p++) {
            l[p] = lg[p];
            mx = fmaxf(mx, l[p]);
        }
        float se = 0.f;
#pragma unroll
        for (int p = 0; p < PP; p++) se += __expf(l[p] - mx);
        float lse = mx + logf(se);
        int lab = qy[tid];
        val = -(l[lab] - lse);
    }
    __shared__ float red[16];
    float s = wsum64(val);
    if ((tid & 63) == 0) red[tid >> 6] = s;
    __syncthreads();
    if (tid == 0) {
        float tot = 0.f;
#pragma unroll
        for (int w = 0; w < 10; w++) tot += red[w];
        out[0] = tot * (1.0f / NIMG_Q);
    }
}

extern "C" void kernel_launch(void* const* d_in, const int* in_sizes, int n_in,
                              void* d_out, int out_size, void* d_ws, size_t ws_size,
                              hipStream_t stream) {
    const float* sup = (const float*)d_in[0];   // support_xf [8,5,640,7,7]
    const float* qry = (const float*)d_in[1];   // query_xf   [8,75,640,7,7]
    const int* qy = (const int*)d_in[3];        // query_y    [8,75]
    float* ws = (float*)d_ws;
    float* out = (float*)d_out;

    stats_kernel<<<NIMG_Q + NIMG_S, 64, 0, stream>>>(sup, qry, ws);
    marga_kernel<<<NIMG_Q, 64, 0, stream>>>(qry, ws);
    margb_kernel<<<NIMG_S * 5, 64, 0, stream>>>(sup, ws);
    emd_kernel<<<NPROB, 256, 0, stream>>>(sup, qry, ws);
    loss_kernel<<<1, 640, 0, stream>>>(ws, qy, out);
}

// Round 2
// 729.713 us; speedup vs baseline: 1.1267x; 1.1267x over previous
//
#include <hip/hip_runtime.h>
#include <math.h>

#define BB 8
#define PP 5
#define QQ 75
#define CC 640
#define HW 49
#define NIMG_Q (BB*QQ)     // 600
#define NIMG_S (BB*PP)     // 40
#define NPROB  (BB*QQ*PP)  // 3000
#define TEMP 12.5f

// workspace layout (float offsets); total ~769K floats ~ 3.1 MB
#define OFF_SGAP   0
#define OFF_QGAP   (OFF_SGAP  + NIMG_S*CC)
#define OFF_SMEAN  (OFF_QGAP  + NIMG_Q*CC)
#define OFF_SINV   (OFF_SMEAN + NIMG_S*HW)
#define OFF_QMEAN  (OFF_SINV  + NIMG_S*HW)
#define OFF_QINV   (OFF_QMEAN + NIMG_Q*HW)
#define OFF_MARGA  (OFF_QINV  + NIMG_Q*HW)
#define OFF_MARGB  (OFF_MARGA + NPROB*HW)
#define OFF_LOGITS (OFF_MARGB + NPROB*HW)

__device__ __forceinline__ float wsum64(float v) {
#pragma unroll
    for (int off = 32; off > 0; off >>= 1) v += __shfl_xor(v, off, 64);
    return v;
}

// ---------------- Kernel 1: per-image stats ----------------
// grid = 640 (600 query imgs + 40 support imgs), block = 256 (4 waves)
__global__ __launch_bounds__(256) void stats_kernel(const float* __restrict__ sup,
                                                    const float* __restrict__ qry,
                                                    float* __restrict__ ws) {
    int img = blockIdx.x;
    int tid = threadIdx.x;
    int lane = tid & 63;
    int wv = tid >> 6;
    const float* X;
    float *gap, *cmean, *cinv;
    if (img < NIMG_Q) {
        X = qry + (size_t)img * CC * HW;
        gap = ws + OFF_QGAP + img * CC;
        cmean = ws + OFF_QMEAN + img * HW;
        cinv = ws + OFF_QINV + img * HW;
    } else {
        int i = img - NIMG_Q;
        X = sup + (size_t)i * CC * HW;
        gap = ws + OFF_SGAP + i * CC;
        cmean = ws + OFF_SMEAN + i * HW;
        cinv = ws + OFF_SINV + i * HW;
    }
    // pass A: column (spatial) stats over channels, 160 channels per wave
    __shared__ float cs_p[4][52], sq_p[4][52];
    float cs = 0.f, sq = 0.f;
    if (lane < HW) {
        for (int c = wv * 160; c < wv * 160 + 160; c++) {
            float v = X[c * HW + lane];
            cs += v;
            sq = fmaf(v, v, sq);
        }
    }
    if (lane < 52) {
        cs_p[wv][lane] = (lane < HW) ? cs : 0.f;
        sq_p[wv][lane] = (lane < HW) ? sq : 0.f;
    }
    __syncthreads();
    if (wv == 0 && lane < HW) {
        float c4 = cs_p[0][lane] + cs_p[1][lane] + cs_p[2][lane] + cs_p[3][lane];
        float s4 = sq_p[0][lane] + sq_p[1][lane] + sq_p[2][lane] + sq_p[3][lane];
        float mu = c4 * (1.0f / CC);
        float nsq = fmaxf(s4 - c4 * c4 * (1.0f / CC), 0.f);
        cmean[lane] = mu;
        cinv[lane] = 1.0f / fmaxf(sqrtf(nsq), 1e-8f);
    }
    // pass B: GAP vector (mean over spatial), 256 threads over 640 channels
    for (int c = tid; c < CC; c += 256) {
        float s = 0.f;
        for (int m = 0; m < HW; m++) s += X[c * HW + m];
        gap[c] = s * (1.0f / HW);
    }
}

// ---------------- Kernel 2: row marginals a (query side, w1) ----------------
// grid = 600 (b,q), block = 256 (4 waves x 160 channels)
__global__ __launch_bounds__(256) void marga_kernel(const float* __restrict__ qry,
                                                    float* __restrict__ ws) {
    int bq = blockIdx.x;
    int b = bq / QQ;
    int tid = threadIdx.x;
    int lane = tid & 63;
    int wv = tid >> 6;
    const float* X = qry + (size_t)bq * CC * HW;
    const float* sg = ws + OFF_SGAP + b * PP * CC;
    float acc[PP] = {0.f, 0.f, 0.f, 0.f, 0.f};
    if (lane < HW) {
        for (int c = wv * 160; c < wv * 160 + 160; c++) {
            float v = X[c * HW + lane];
#pragma unroll
            for (int p = 0; p < PP; p++) acc[p] = fmaf(v, sg[p * CC + c], acc[p]);
        }
    }
    __shared__ float part[4][PP][52];
    if (lane < 52) {
#pragma unroll
        for (int p = 0; p < PP; p++) part[wv][p][lane] = (lane < HW) ? acc[p] : 0.f;
    }
    __syncthreads();
    if (wv == 0) {
#pragma unroll
        for (int p = 0; p < PP; p++) {
            float a = 0.f;
            if (lane < 52)
                a = part[0][p][lane] + part[1][p][lane] + part[2][p][lane] + part[3][p][lane];
            float w = (lane < HW) ? (fmaxf(a, 0.f) + 1.01e-3f) : 0.f;
            float s = wsum64(w);
            if (lane < HW) ws[OFF_MARGA + (bq * PP + p) * HW + lane] = w / s;
        }
    }
}

// ---------------- Kernel 3: col marginals b (support side, w2) ----------------
// grid = 200, block = 256 (4 waves x 160 channels); 15 q's per block
__global__ __launch_bounds__(256) void margb_kernel(const float* __restrict__ sup,
                                                    float* __restrict__ ws) {
    int id = blockIdx.x;
    int qc = id % 5;
    int bp = id / 5;
    int b = bp / PP;
    int p = bp % PP;
    int tid = threadIdx.x;
    int lane = tid & 63;
    int wv = tid >> 6;
    const float* X = sup + (size_t)bp * CC * HW;
    const float* qg = ws + OFF_QGAP + (b * QQ + qc * 15) * CC;
    float acc[15];
#pragma unroll
    for (int i = 0; i < 15; i++) acc[i] = 0.f;
    if (lane < HW) {
        for (int c = wv * 160; c < wv * 160 + 160; c++) {
            float sv = X[c * HW + lane];
#pragma unroll
            for (int qq = 0; qq < 15; qq++)
                acc[qq] = fmaf(sv, qg[qq * CC + c], acc[qq]);
        }
    }
    __shared__ float part[4][15][52];
    if (lane < 52) {
#pragma unroll
        for (int qq = 0; qq < 15; qq++) part[wv][qq][lane] = (lane < HW) ? acc[qq] : 0.f;
    }
    __syncthreads();
    if (wv == 0) {
#pragma unroll
        for (int qq = 0; qq < 15; qq++) {
            float a = 0.f;
            if (lane < 52)
                a = part[0][qq][lane] + part[1][qq][lane] + part[2][qq][lane] + part[3][qq][lane];
            int q = qc * 15 + qq;
            float w = (lane < HW) ? (fmaxf(a, 0.f) + 1.01e-3f) : 0.f;
            float s = wsum64(w);
            if (lane < HW) ws[OFF_MARGB + ((b * QQ + q) * PP + p) * HW + lane] = w / s;
        }
    }
}

// ---------------- Kernel 4: fused S-GEMM + Sinkhorn + logit ----------------
// grid = 3000 (one problem per block), block = 256
// __launch_bounds__(256,2): VGPR budget 256 so kr[52]+kt[52] stay in registers
// (round 1: default heuristic capped at 84 VGPRs -> 95 MB of scratch spills).
__global__ __launch_bounds__(256, 2) void emd_kernel(const float* __restrict__ sup,
                                                     const float* __restrict__ qry,
                                                     float* __restrict__ ws) {
    __shared__ __align__(16) float AB[2][32][64];   // 16 KB staging; S_lds aliases it
    __shared__ __align__(16) float vbuf[52];
    __shared__ __align__(16) float ubuf[52];
    float (*S_lds)[53] = (float (*)[53])(&AB[0][0][0]);  // 50*53=2650 <= 4096 floats

    int prob = blockIdx.x;
    int p = prob % PP;
    int bq = prob / PP;          // b*75+q
    int b = bq / QQ;
    int tid = threadIdx.x;
    int lane = tid & 63;
    int wv = tid >> 6;
    int sw = prob & 3;           // Sinkhorn wave: vary per block to spread over SIMDs
    // 13x13 thread grid -> 52x52 output tile (only 49x49 needed; was 64x64 = 1.7x waste)
    int tyc = tid / 13;
    int txc = tid - tyc * 13;
    bool active = tid < 169;

    const float* Xq = qry + (size_t)bq * CC * HW;
    const float* Xs = sup + (size_t)(b * PP + p) * CC * HW;

    float qm = 0.f, qi = 0.f, sm = 0.f, si = 0.f;
    if (lane < HW) {
        qm = ws[OFF_QMEAN + bq * HW + lane];
        qi = ws[OFF_QINV + bq * HW + lane];
        sm = ws[OFF_SMEAN + (b * PP + p) * HW + lane];
        si = ws[OFF_SINV + (b * PP + p) * HW + lane];
    }

    float acc[4][4];
#pragma unroll
    for (int i = 0; i < 4; i++)
#pragma unroll
        for (int j = 0; j < 4; j++) acc[i][j] = 0.f;

    for (int c0 = 0; c0 < CC; c0 += 32) {
        __syncthreads();
        // stage normalized chunks: each wave loads 8 rows of each array
        for (int cl = wv; cl < 32; cl += 4) {
            int c = c0 + cl;
            float av = 0.f, bv = 0.f;
            if (lane < HW) {
                av = (Xq[c * HW + lane] - qm) * qi;
                bv = (Xs[c * HW + lane] - sm) * si;
            }
            AB[0][cl][lane] = av;
            AB[1][cl][lane] = bv;
        }
        __syncthreads();
        if (active) {
#pragma unroll
            for (int cl = 0; cl < 32; cl++) {
                float4 a4 = *(const float4*)&AB[0][cl][4 * tyc];
                float4 b4 = *(const float4*)&AB[1][cl][4 * txc];
                float av[4] = {a4.x, a4.y, a4.z, a4.w};
                float bv[4] = {b4.x, b4.y, b4.z, b4.w};
#pragma unroll
                for (int i = 0; i < 4; i++)
#pragma unroll
                    for (int j = 0; j < 4; j++) acc[i][j] = fmaf(av[i], bv[j], acc[i][j]);
            }
        }
    }

    __syncthreads();   // staging buffers dead; safe to overwrite with S
    if (active) {
#pragma unroll
        for (int i = 0; i < 4; i++) {
#pragma unroll
            for (int j = 0; j < 4; j++) {
                int m = 4 * tyc + i, n = 4 * txc + j;
                if (m < HW && n < HW) S_lds[m][n] = acc[i][j];
            }
        }
    }
    __syncthreads();
    if (wv != sw) return;  // one wave runs Sinkhorn barrier-free

    float am = 0.f, bm = 0.f;
    if (lane < HW) {
        am = ws[OFF_MARGA + prob * HW + lane];
        bm = ws[OFF_MARGB + prob * HW + lane];
    }
    int lr = (lane < HW) ? lane : 0;

    // K row (kr) and K column (kt) in registers; K = exp((S-1)/eps) = exp(20S-20)
    float kr[52], kt[52];
#pragma unroll
    for (int j = 0; j < 52; j++) {
        float krv = 0.f, ktv = 0.f;
        if (j < HW) {
            krv = __expf(fmaf(20.f, S_lds[lr][j], -20.f));
            ktv = __expf(fmaf(20.f, S_lds[j][lr], -20.f));
        }
        bool act = (lane < HW);
        kr[j] = act ? krv : 0.f;
        kt[j] = act ? ktv : 0.f;
    }

    if (lane < 52) {
        vbuf[lane] = (lane < HW) ? 1.f : 0.f;
        ubuf[lane] = 0.f;
    }
    __threadfence_block();

    float u = 0.f;
    for (int it = 0; it < 100; it++) {
        // u = a / (K v)
        float t0 = 0.f, t1 = 0.f, t2 = 0.f, t3 = 0.f;
#pragma unroll
        for (int g = 0; g < 13; g++) {
            float4 v4 = *(const float4*)&vbuf[4 * g];
            t0 = fmaf(kr[4 * g + 0], v4.x, t0);
            t1 = fmaf(kr[4 * g + 1], v4.y, t1);
            t2 = fmaf(kr[4 * g + 2], v4.z, t2);
            t3 = fmaf(kr[4 * g + 3], v4.w, t3);
        }
        float t = (t0 + t1) + (t2 + t3);
        u = am * __builtin_amdgcn_rcpf(t);
        if (lane < HW) ubuf[lane] = u;
        __threadfence_block();
        // v = b / (K^T u)
        float s0 = 0.f, s1 = 0.f, s2 = 0.f, s3 = 0.f;
#pragma unroll
        for (int g = 0; g < 13; g++) {
            float4 u4 = *(const float4*)&ubuf[4 * g];
            s0 = fmaf(kt[4 * g + 0], u4.x, s0);
            s1 = fmaf(kt[4 * g + 1], u4.y, s1);
            s2 = fmaf(kt[4 * g + 2], u4.z, s2);
            s3 = fmaf(kt[4 * g + 3], u4.w, s3);
        }
        float t2s = (s0 + s1) + (s2 + s3);
        float v = bm * __builtin_amdgcn_rcpf(t2s);
        if (lane < HW) vbuf[lane] = v;
        __threadfence_block();
    }

    // logit = T * sum_{m,n} S_mn * u_m K_mn v_n
    float ssum = 0.f;
#pragma unroll
    for (int g = 0; g < 13; g++) {
        float4 v4 = *(const float4*)&vbuf[4 * g];
        float vv[4] = {v4.x, v4.y, v4.z, v4.w};
#pragma unroll
        for (int k = 0; k < 4; k++) {
            int j = 4 * g + k;
            if (j < HW) ssum = fmaf(S_lds[lr][j] * kr[j], vv[k], ssum);
        }
    }
    float contrib = (lane < HW) ? (u * ssum) : 0.f;
    float tot = wsum64(contrib);
    if (lane == 0) ws[OFF_LOGITS + prob] = TEMP * tot;
}

// ---------------- Kernel 5: cross-entropy loss ----------------
// grid = 1, block = 640
__global__ __launch_bounds__(640) void loss_kernel(const float* __restrict__ ws,
                                                   const int* __restrict__ qy,
                                                   float* __restrict__ out) {
    int tid = threadIdx.x;
    float val = 0.f;
    if (tid < NIMG_Q) {
        const float* lg = ws + OFF_LOGITS + tid * PP;
        float l[PP];
        float mx = -1e30f;
#pragma unroll
        for (int p = 0; p < PP; p++) {
            l[p] = lg[p];
            mx = fmaxf(mx, l[p]);
        }
        float se = 0.f;
#pragma unroll
        for (int p = 0; p < PP; p++) se += __expf(l[p] - mx);
        float lse = mx + logf(se);
        int lab = qy[tid];
        val = -(l[lab] - lse);
    }
    __shared__ float red[16];
    float s = wsum64(val);
    if ((tid & 63) == 0) red[tid >> 6] = s;
    __syncthreads();
    if (tid == 0) {
        float tot = 0.f;
#pragma unroll
        for (int w = 0; w < 10; w++) tot += red[w];
        out[0] = tot * (1.0f / NIMG_Q);
    }
}

extern "C" void kernel_launch(void* const* d_in, const int* in_sizes, int n_in,
                              void* d_out, int out_size, void* d_ws, size_t ws_size,
                              hipStream_t stream) {
    const float* sup = (const float*)d_in[0];   // support_xf [8,5,640,7,7]
    const float* qry = (const float*)d_in[1];   // query_xf   [8,75,640,7,7]
    const int* qy = (const int*)d_in[3];        // query_y    [8,75]
    float* ws = (float*)d_ws;
    float* out = (float*)d_out;

    stats_kernel<<<NIMG_Q + NIMG_S, 256, 0, stream>>>(sup, qry, ws);
    marga_kernel<<<NIMG_Q, 256, 0, stream>>>(qry, ws);
    margb_kernel<<<NIMG_S * 5, 256, 0, stream>>>(sup, ws);
    emd_kernel<<<NPROB, 256, 0, stream>>>(sup, qry, ws);
    loss_kernel<<<1, 640, 0, stream>>>(ws, qy, out);
}

// Round 3
// 728.974 us; speedup vs baseline: 1.1278x; 1.0010x over previous
//
#include <hip/hip_runtime.h>
#include <math.h>

#define BB 8
#define PP 5
#define QQ 75
#define CC 640
#define HW 49
#define NIMG_Q (BB*QQ)     // 600
#define NIMG_S (BB*PP)     // 40
#define NPROB  (BB*QQ*PP)  // 3000
#define TEMP 12.5f

// workspace layout (float offsets); total ~769K floats ~ 3.1 MB
#define OFF_SGAP   0
#define OFF_QGAP   (OFF_SGAP  + NIMG_S*CC)
#define OFF_SMEAN  (OFF_QGAP  + NIMG_Q*CC)
#define OFF_SINV   (OFF_SMEAN + NIMG_S*HW)
#define OFF_QMEAN  (OFF_SINV  + NIMG_S*HW)
#define OFF_QINV   (OFF_QMEAN + NIMG_Q*HW)
#define OFF_MARGA  (OFF_QINV  + NIMG_Q*HW)
#define OFF_MARGB  (OFF_MARGA + NPROB*HW)
#define OFF_LOGITS (OFF_MARGB + NPROB*HW)

__device__ __forceinline__ float wsum64(float v) {
#pragma unroll
    for (int off = 32; off > 0; off >>= 1) v += __shfl_xor(v, off, 64);
    return v;
}

// ---------------- Kernel 1: per-image stats ----------------
// grid = 640 (600 query imgs + 40 support imgs), block = 256 (4 waves)
__global__ __launch_bounds__(256) void stats_kernel(const float* __restrict__ sup,
                                                    const float* __restrict__ qry,
                                                    float* __restrict__ ws) {
    int img = blockIdx.x;
    int tid = threadIdx.x;
    int lane = tid & 63;
    int wv = tid >> 6;
    const float* X;
    float *gap, *cmean, *cinv;
    if (img < NIMG_Q) {
        X = qry + (size_t)img * CC * HW;
        gap = ws + OFF_QGAP + img * CC;
        cmean = ws + OFF_QMEAN + img * HW;
        cinv = ws + OFF_QINV + img * HW;
    } else {
        int i = img - NIMG_Q;
        X = sup + (size_t)i * CC * HW;
        gap = ws + OFF_SGAP + i * CC;
        cmean = ws + OFF_SMEAN + i * HW;
        cinv = ws + OFF_SINV + i * HW;
    }
    // pass A: column (spatial) stats over channels, 160 channels per wave
    __shared__ float cs_p[4][52], sq_p[4][52];
    float cs = 0.f, sq = 0.f;
    if (lane < HW) {
        for (int c = wv * 160; c < wv * 160 + 160; c++) {
            float v = X[c * HW + lane];
            cs += v;
            sq = fmaf(v, v, sq);
        }
    }
    if (lane < 52) {
        cs_p[wv][lane] = (lane < HW) ? cs : 0.f;
        sq_p[wv][lane] = (lane < HW) ? sq : 0.f;
    }
    __syncthreads();
    if (wv == 0 && lane < HW) {
        float c4 = cs_p[0][lane] + cs_p[1][lane] + cs_p[2][lane] + cs_p[3][lane];
        float s4 = sq_p[0][lane] + sq_p[1][lane] + sq_p[2][lane] + sq_p[3][lane];
        float mu = c4 * (1.0f / CC);
        float nsq = fmaxf(s4 - c4 * c4 * (1.0f / CC), 0.f);
        cmean[lane] = mu;
        cinv[lane] = 1.0f / fmaxf(sqrtf(nsq), 1e-8f);
    }
    // pass B: GAP vector (mean over spatial), 256 threads over 640 channels
    for (int c = tid; c < CC; c += 256) {
        float s = 0.f;
        for (int m = 0; m < HW; m++) s += X[c * HW + m];
        gap[c] = s * (1.0f / HW);
    }
}

// ---------------- Kernel 2: row marginals a (query side, w1) ----------------
// grid = 600 (b,q), block = 256 (4 waves x 160 channels)
__global__ __launch_bounds__(256) void marga_kernel(const float* __restrict__ qry,
                                                    float* __restrict__ ws) {
    int bq = blockIdx.x;
    int b = bq / QQ;
    int tid = threadIdx.x;
    int lane = tid & 63;
    int wv = tid >> 6;
    const float* X = qry + (size_t)bq * CC * HW;
    const float* sg = ws + OFF_SGAP + b * PP * CC;
    float acc[PP] = {0.f, 0.f, 0.f, 0.f, 0.f};
    if (lane < HW) {
        for (int c = wv * 160; c < wv * 160 + 160; c++) {
            float v = X[c * HW + lane];
#pragma unroll
            for (int p = 0; p < PP; p++) acc[p] = fmaf(v, sg[p * CC + c], acc[p]);
        }
    }
    __shared__ float part[4][PP][52];
    if (lane < 52) {
#pragma unroll
        for (int p = 0; p < PP; p++) part[wv][p][lane] = (lane < HW) ? acc[p] : 0.f;
    }
    __syncthreads();
    if (wv == 0) {
#pragma unroll
        for (int p = 0; p < PP; p++) {
            float a = 0.f;
            if (lane < 52)
                a = part[0][p][lane] + part[1][p][lane] + part[2][p][lane] + part[3][p][lane];
            float w = (lane < HW) ? (fmaxf(a, 0.f) + 1.01e-3f) : 0.f;
            float s = wsum64(w);
            if (lane < HW) ws[OFF_MARGA + (bq * PP + p) * HW + lane] = w / s;
        }
    }
}

// ---------------- Kernel 3: col marginals b (support side, w2) ----------------
// grid = 200, block = 256 (4 waves x 160 channels); 15 q's per block
__global__ __launch_bounds__(256) void margb_kernel(const float* __restrict__ sup,
                                                    float* __restrict__ ws) {
    int id = blockIdx.x;
    int qc = id % 5;
    int bp = id / 5;
    int b = bp / PP;
    int p = bp % PP;
    int tid = threadIdx.x;
    int lane = tid & 63;
    int wv = tid >> 6;
    const float* X = sup + (size_t)bp * CC * HW;
    const float* qg = ws + OFF_QGAP + (b * QQ + qc * 15) * CC;
    float acc[15];
#pragma unroll
    for (int i = 0; i < 15; i++) acc[i] = 0.f;
    if (lane < HW) {
        for (int c = wv * 160; c < wv * 160 + 160; c++) {
            float sv = X[c * HW + lane];
#pragma unroll
            for (int qq = 0; qq < 15; qq++)
                acc[qq] = fmaf(sv, qg[qq * CC + c], acc[qq]);
        }
    }
    __shared__ float part[4][15][52];
    if (lane < 52) {
#pragma unroll
        for (int qq = 0; qq < 15; qq++) part[wv][qq][lane] = (lane < HW) ? acc[qq] : 0.f;
    }
    __syncthreads();
    if (wv == 0) {
#pragma unroll
        for (int qq = 0; qq < 15; qq++) {
            float a = 0.f;
            if (lane < 52)
                a = part[0][qq][lane] + part[1][qq][lane] + part[2][qq][lane] + part[3][qq][lane];
            int q = qc * 15 + qq;
            float w = (lane < HW) ? (fmaxf(a, 0.f) + 1.01e-3f) : 0.f;
            float s = wsum64(w);
            if (lane < HW) ws[OFF_MARGB + ((b * QQ + q) * PP + p) * HW + lane] = w / s;
        }
    }
}

// ---------------- Kernel 4: fused S-GEMM + Sinkhorn + logit ----------------
// grid = 3000 (one problem per block), block = 256
// kr/kt MUST be named float4 locals (not arrays): float kr[52] allocas are
// variably-indexed at SROA time -> never promoted -> 95 MB scratch traffic
// (rounds 1-2: VGPR_Count=84, WRITE_SIZE=95MB). Named vectors mem2reg cleanly.
#define FOR12(M) M(0) M(1) M(2) M(3) M(4) M(5) M(6) M(7) M(8) M(9) M(10) M(11)
#define KEXP(r, c) __expf(fmaf(20.f, S_lds[r][c], -20.f))

__global__ __launch_bounds__(256, 2) void emd_kernel(const float* __restrict__ sup,
                                                     const float* __restrict__ qry,
                                                     float* __restrict__ ws) {
    __shared__ __align__(16) float AB[2][32][64];   // 16 KB staging; S_lds aliases it
    __shared__ __align__(16) float vbuf[52];
    __shared__ __align__(16) float ubuf[52];
    float (*S_lds)[53] = (float (*)[53])(&AB[0][0][0]);  // 50*53=2650 <= 4096 floats

    int prob = blockIdx.x;
    int p = prob % PP;
    int bq = prob / PP;          // b*75+q
    int b = bq / QQ;
    int tid = threadIdx.x;
    int lane = tid & 63;
    int wv = tid >> 6;
    int sw = prob & 3;           // Sinkhorn wave: vary per block to spread over SIMDs
    // 13x13 thread grid -> 52x52 output tile (only 49x49 needed)
    int tyc = tid / 13;
    int txc = tid - tyc * 13;
    bool active = tid < 169;

    const float* Xq = qry + (size_t)bq * CC * HW;
    const float* Xs = sup + (size_t)(b * PP + p) * CC * HW;

    float qm = 0.f, qi = 0.f, sm = 0.f, si = 0.f;
    if (lane < HW) {
        qm = ws[OFF_QMEAN + bq * HW + lane];
        qi = ws[OFF_QINV + bq * HW + lane];
        sm = ws[OFF_SMEAN + (b * PP + p) * HW + lane];
        si = ws[OFF_SINV + (b * PP + p) * HW + lane];
    }

    float acc[4][4];
#pragma unroll
    for (int i = 0; i < 4; i++)
#pragma unroll
        for (int j = 0; j < 4; j++) acc[i][j] = 0.f;

    for (int c0 = 0; c0 < CC; c0 += 32) {
        __syncthreads();
        for (int cl = wv; cl < 32; cl += 4) {
            int c = c0 + cl;
            float av = 0.f, bv = 0.f;
            if (lane < HW) {
                av = (Xq[c * HW + lane] - qm) * qi;
                bv = (Xs[c * HW + lane] - sm) * si;
            }
            AB[0][cl][lane] = av;
            AB[1][cl][lane] = bv;
        }
        __syncthreads();
        if (active) {
#pragma unroll
            for (int cl = 0; cl < 32; cl++) {
                float4 a4 = *(const float4*)&AB[0][cl][4 * tyc];
                float4 b4 = *(const float4*)&AB[1][cl][4 * txc];
                float av[4] = {a4.x, a4.y, a4.z, a4.w};
                float bv[4] = {b4.x, b4.y, b4.z, b4.w};
#pragma unroll
                for (int i = 0; i < 4; i++)
#pragma unroll
                    for (int j = 0; j < 4; j++) acc[i][j] = fmaf(av[i], bv[j], acc[i][j]);
            }
        }
    }

    __syncthreads();   // staging buffers dead; safe to overwrite with S
    if (active) {
#pragma unroll
        for (int i = 0; i < 4; i++) {
#pragma unroll
            for (int j = 0; j < 4; j++) {
                int m = 4 * tyc + i, n = 4 * txc + j;
                if (m < HW && n < HW) S_lds[m][n] = acc[i][j];
            }
        }
    }
    __syncthreads();
    if (wv != sw) return;  // one wave runs Sinkhorn barrier-free

    float am = 0.f, bm = 0.f;
    if (lane < HW) {
        am = ws[OFF_MARGA + prob * HW + lane];
        bm = ws[OFF_MARGB + prob * HW + lane];
    }
    int lr = (lane < HW) ? lane : 0;

    // K row (kr*) and K column (kt*) in named float4 registers.
    // K = exp((S-1)/eps) = exp(20S-20). Inactive lanes (>=HW) compute
    // garbage-but-finite values; they are neutralized by am=bm=0.
    float4 kr0, kr1, kr2, kr3, kr4, kr5, kr6, kr7, kr8, kr9, kr10, kr11, kr12;
    float4 kt0, kt1, kt2, kt3, kt4, kt5, kt6, kt7, kt8, kt9, kt10, kt11, kt12;
#define KINIT(g)                                                            \
    kr##g = make_float4(KEXP(lr, 4*(g)+0), KEXP(lr, 4*(g)+1),               \
                        KEXP(lr, 4*(g)+2), KEXP(lr, 4*(g)+3));              \
    kt##g = make_float4(KEXP(4*(g)+0, lr), KEXP(4*(g)+1, lr),               \
                        KEXP(4*(g)+2, lr), KEXP(4*(g)+3, lr));
    FOR12(KINIT)
#undef KINIT
    // j=48 only; cols/rows 49..51 are uninitialized LDS padding -> must be 0
    kr12 = make_float4(KEXP(lr, 48), 0.f, 0.f, 0.f);
    kt12 = make_float4(KEXP(48, lr), 0.f, 0.f, 0.f);

    if (lane < 52) {
        vbuf[lane] = (lane < HW) ? 1.f : 0.f;
        ubuf[lane] = 0.f;
    }
    __threadfence_block();

    float u = 0.f;
    for (int it = 0; it < 100; it++) {
        // u = a / (K v)
        float t0 = 0.f, t1 = 0.f, t2 = 0.f, t3 = 0.f;
#define RFMA(g) { float4 v4 = *(const float4*)&vbuf[4*(g)];                 \
        t0 = fmaf(kr##g.x, v4.x, t0); t1 = fmaf(kr##g.y, v4.y, t1);         \
        t2 = fmaf(kr##g.z, v4.z, t2); t3 = fmaf(kr##g.w, v4.w, t3); }
        FOR12(RFMA) RFMA(12)
#undef RFMA
        float t = (t0 + t1) + (t2 + t3);
        u = am * __builtin_amdgcn_rcpf(t);
        if (lane < HW) ubuf[lane] = u;
        __threadfence_block();
        // v = b / (K^T u)
        float s0 = 0.f, s1 = 0.f, s2 = 0.f, s3 = 0.f;
#define CFMA(g) { float4 u4 = *(const float4*)&ubuf[4*(g)];                 \
        s0 = fmaf(kt##g.x, u4.x, s0); s1 = fmaf(kt##g.y, u4.y, s1);         \
        s2 = fmaf(kt##g.z, u4.z, s2); s3 = fmaf(kt##g.w, u4.w, s3); }
        FOR12(CFMA) CFMA(12)
#undef CFMA
        float t2s = (s0 + s1) + (s2 + s3);
        float v = bm * __builtin_amdgcn_rcpf(t2s);
        if (lane < HW) vbuf[lane] = v;
        __threadfence_block();
    }

    // logit = T * sum_{m,n} S_mn * u_m K_mn v_n
    float ssum = 0.f;
#define SSUM(g) { float4 v4 = *(const float4*)&vbuf[4*(g)];                 \
        ssum = fmaf(S_lds[lr][4*(g)+0] * kr##g.x, v4.x, ssum);              \
        ssum = fmaf(S_lds[lr][4*(g)+1] * kr##g.y, v4.y, ssum);              \
        ssum = fmaf(S_lds[lr][4*(g)+2] * kr##g.z, v4.z, ssum);              \
        ssum = fmaf(S_lds[lr][4*(g)+3] * kr##g.w, v4.w, ssum); }
    FOR12(SSUM)
#undef SSUM
    ssum = fmaf(S_lds[lr][48] * kr12.x, vbuf[48], ssum);
    float contrib = (lane < HW) ? (u * ssum) : 0.f;
    float tot = wsum64(contrib);
    if (lane == 0) ws[OFF_LOGITS + prob] = TEMP * tot;
}

// ---------------- Kernel 5: cross-entropy loss ----------------
// grid = 1, block = 640
__global__ __launch_bounds__(640) void loss_kernel(const float* __restrict__ ws,
                                                   const int* __restrict__ qy,
                                                   float* __restrict__ out) {
    int tid = threadIdx.x;
    float val = 0.f;
    if (tid < NIMG_Q) {
        const float* lg = ws + OFF_LOGITS + tid * PP;
        float l[PP];
        float mx = -1e30f;
#pragma unroll
        for (int p = 0; p < PP; p++) {
            l[p] = lg[p];
            mx = fmaxf(mx, l[p]);
        }
        float se = 0.f;
#pragma unroll
        for (int p = 0; p < PP; p++) se += __expf(l[p] - mx);
        float lse = mx + logf(se);
        int lab = qy[tid];
        val = -(l[lab] - lse);
    }
    __shared__ float red[16];
    float s = wsum64(val);
    if ((tid & 63) == 0) red[tid >> 6] = s;
    __syncthreads();
    if (tid == 0) {
        float tot = 0.f;
#pragma unroll
        for (int w = 0; w < 10; w++) tot += red[w];
        out[0] = tot * (1.0f / NIMG_Q);
    }
}

extern "C" void kernel_launch(void* const* d_in, const int* in_sizes, int n_in,
                              void* d_out, int out_size, void* d_ws, size_t ws_size,
                              hipStream_t stream) {
    const float* sup = (const float*)d_in[0];   // support_xf [8,5,640,7,7]
    const float* qry = (const float*)d_in[1];   // query_xf   [8,75,640,7,7]
    const int* qy = (const int*)d_in[3];        // query_y    [8,75]
    float* ws = (float*)d_ws;
    float* out = (float*)d_out;

    stats_kernel<<<NIMG_Q + NIMG_S, 256, 0, stream>>>(sup, qry, ws);
    marga_kernel<<<NIMG_Q, 256, 0, stream>>>(qry, ws);
    margb_kernel<<<NIMG_S * 5, 256, 0, stream>>>(sup, ws);
    emd_kernel<<<NPROB, 256, 0, stream>>>(sup, qry, ws);
    loss_kernel<<<1, 640, 0, stream>>>(ws, qy, out);
}